// Round 2
// baseline (663.647 us; speedup 1.0000x reference)
//
#include <hip/hip_runtime.h>
#include <hip/hip_bf16.h>
#include <stdint.h>

// QuantizedViTOutput: fake-quant(W, 8-bit per-row symmetric) GEMM + bias + residual.
// M=16384 (B*S), K=4096 (D_FF), N=1024 (D). Inputs fp32, OUTPUT FP32 (reference is all-fp32).
// Round 2: same m97-structure GEMM; epilogue now stores float32 (round-1 wrote bf16 bits
// into a float* buffer -> harness read garbage).

#define M_TOTAL 16384
#define KDIM    4096
#define NDIM    1024
#define BM      128
#define BN      128
#define BK      64

using f32x4  = __attribute__((ext_vector_type(4))) float;
using bf16x8 = __attribute__((ext_vector_type(8))) __bf16;
using u16x8  = __attribute__((ext_vector_type(8))) unsigned short;

__device__ __forceinline__ unsigned short f32_to_bf16_bits(float f) {
  union { float f; uint32_t u; } x; x.f = f;
  uint32_t r = x.u + 0x7FFFu + ((x.u >> 16) & 1u);   // RNE
  return (unsigned short)(r >> 16);
}

__device__ __forceinline__ void async_copy16(const void* g, void* l) {
  __builtin_amdgcn_global_load_lds(
      (const __attribute__((address_space(1))) void*)g,
      (__attribute__((address_space(3))) void*)l,
      16, 0, 0);   // 16B/lane, wave-uniform LDS base + lane*16
}

// ---------------- kernel 1: per-output-channel fake-quant of W -> bf16 ----------------
// W: [NDIM][KDIM] fp32. One block per row; 256 threads x 16 elems.
__global__ __launch_bounds__(256) void quantize_w_kernel(
    const float* __restrict__ W, unsigned short* __restrict__ Bq) {
  const int row = blockIdx.x;
  const int t   = threadIdx.x;
  const f32x4* wv = (const f32x4*)(W + (size_t)row * KDIM);

  f32x4 v[4];
  float m = 0.0f;
#pragma unroll
  for (int i = 0; i < 4; ++i) {
    v[i] = wv[t * 4 + i];
#pragma unroll
    for (int j = 0; j < 4; ++j) m = fmaxf(m, fabsf(v[i][j]));
  }
#pragma unroll
  for (int off = 32; off >= 1; off >>= 1) m = fmaxf(m, __shfl_xor(m, off));
  __shared__ float smax[4];
  if ((t & 63) == 0) smax[t >> 6] = m;
  __syncthreads();
  m = fmaxf(fmaxf(smax[0], smax[1]), fmaxf(smax[2], smax[3]));

  const float scale = fmaxf(m, 1e-8f) / 127.0f;   // same op order as reference

  u16x8 o[2];
#pragma unroll
  for (int i = 0; i < 16; ++i) {
    float w = v[i >> 2][i & 3];
    float q = rintf(w / scale);                    // fp32 IEEE div + RNE, matches jnp.round
    q = fminf(127.0f, fmaxf(-128.0f, q));
    o[i >> 3][i & 7] = f32_to_bf16_bits(q * scale);
  }
  u16x8* dst = (u16x8*)(Bq + (size_t)row * KDIM + t * 16);
  dst[0] = o[0];
  dst[1] = o[1];
}

// ---------------- kernel 2: cast hidden fp32 -> bf16 (vectorized) ----------------
__global__ __launch_bounds__(256) void cast_hidden_kernel(
    const float* __restrict__ A, unsigned short* __restrict__ Ab, int n8) {
  const int stride = gridDim.x * blockDim.x;
  for (int i = blockIdx.x * blockDim.x + threadIdx.x; i < n8; i += stride) {
    const f32x4* src = (const f32x4*)A + (size_t)i * 2;
    f32x4 a = src[0], b = src[1];
    u16x8 o;
#pragma unroll
    for (int j = 0; j < 4; ++j) o[j]     = f32_to_bf16_bits(a[j]);
#pragma unroll
    for (int j = 0; j < 4; ++j) o[4 + j] = f32_to_bf16_bits(b[j]);
    ((u16x8*)Ab)[i] = o;
  }
}

// ---------------- kernel 3: bf16 MFMA GEMM + bias + residual -> fp32 ----------------
// A: [M][K] bf16, Bq: [N][K] bf16 (NT: both K-contiguous). out[m][n] = A.Bq^T + bias + res.
__global__ __launch_bounds__(256) void gemm_bias_res_kernel(
    const unsigned short* __restrict__ A,
    const unsigned short* __restrict__ Bq,
    const float* __restrict__ bias,
    const float* __restrict__ res,
    float* __restrict__ out) {
  __shared__ unsigned short As[BM * BK];   // [128][64] linear, row-major
  __shared__ unsigned short Bs[BN * BK];

  const int nwg = (M_TOTAL / BM) * (NDIM / BN);       // 1024, % 8 == 0
  int bid = blockIdx.x;
  bid = (bid & 7) * (nwg >> 3) + (bid >> 3);          // XCD-bijective swizzle
  const int nb = bid & 7;                              // N fastest: neighbors share A panel
  const int mb = bid >> 3;

  const int t    = threadIdx.x;
  const int lane = t & 63;
  const int wid  = t >> 6;            // 4 waves, 2x2 of 64x64
  const int wm   = wid >> 1;
  const int wn   = wid & 1;

  const int m0 = mb * BM;
  const int n0 = nb * BN;

  // staging addressing: per wave-instr, 64 lanes x 16B = 8 rows of 64 bf16
  const int srow = lane >> 3;
  const int scol = (lane & 7) * 8;
  const unsigned short* ag = A  + (size_t)(m0 + wid * 32 + srow) * KDIM + scol;
  const unsigned short* bg = Bq + (size_t)(n0 + wid * 32 + srow) * KDIM + scol;

  f32x4 acc[4][4];
  const f32x4 zero = {0.f, 0.f, 0.f, 0.f};
#pragma unroll
  for (int i = 0; i < 4; ++i)
#pragma unroll
    for (int j = 0; j < 4; ++j) acc[i][j] = zero;

  const int fr = lane & 15;       // fragment row (A: m-row, B: n-col)
  const int kg = lane >> 4;       // k-group 0..3 (x8 elems)

  for (int k0 = 0; k0 < KDIM; k0 += BK) {
    if (k0) __syncthreads();
#pragma unroll
    for (int i = 0; i < 4; ++i) {
      async_copy16(ag + k0 + i * 8 * KDIM, &As[(wid * 32 + i * 8) * BK]);
      async_copy16(bg + k0 + i * 8 * KDIM, &Bs[(wid * 32 + i * 8) * BK]);
    }
    __syncthreads();   // compiler drains vmcnt before s_barrier -> tiles ready

#pragma unroll
    for (int kk = 0; kk < 2; ++kk) {
      bf16x8 a[4], b[4];
#pragma unroll
      for (int i = 0; i < 4; ++i) {
        a[i] = *(const bf16x8*)&As[(wm * 64 + i * 16 + fr) * BK + kk * 32 + kg * 8];
        b[i] = *(const bf16x8*)&Bs[(wn * 64 + i * 16 + fr) * BK + kk * 32 + kg * 8];
      }
#pragma unroll
      for (int i = 0; i < 4; ++i)
#pragma unroll
        for (int j = 0; j < 4; ++j)
          acc[i][j] = __builtin_amdgcn_mfma_f32_16x16x32_bf16(a[i], b[j], acc[i][j], 0, 0, 0);
    }
  }

  // epilogue: C/D layout col=lane&15, row=(lane>>4)*4+reg (verified m89/m91)
  const int col = lane & 15;
  const int rg  = (lane >> 4) * 4;
#pragma unroll
  for (int j = 0; j < 4; ++j) {
    const int d = n0 + wn * 64 + j * 16 + col;
    const float bb = bias[d];
#pragma unroll
    for (int i = 0; i < 4; ++i) {
      const int mrow = m0 + wm * 64 + i * 16 + rg;
#pragma unroll
      for (int r = 0; r < 4; ++r) {
        const size_t idx = (size_t)(mrow + r) * NDIM + d;
        out[idx] = acc[i][j][r] + bb + res[idx];   // fp32 store
      }
    }
  }
}

extern "C" void kernel_launch(void* const* d_in, const int* in_sizes, int n_in,
                              void* d_out, int out_size, void* d_ws, size_t ws_size,
                              hipStream_t stream) {
  const float* hidden = (const float*)d_in[0];   // [16,1024,4096] fp32
  const float* resid  = (const float*)d_in[1];   // [16,1024,1024] fp32
  const float* W      = (const float*)d_in[2];   // [1024,4096] fp32
  const float* bias   = (const float*)d_in[3];   // [1024] fp32
  float* out          = (float*)d_out;           // [16,1024,1024] fp32

  // workspace: A-bf16 (134.2 MB) + W-fq bf16 (8.4 MB) = 142.7 MB
  unsigned short* Abf = (unsigned short*)d_ws;
  unsigned short* Bq  = Abf + (size_t)M_TOTAL * KDIM;

  quantize_w_kernel<<<NDIM, 256, 0, stream>>>(W, Bq);
  cast_hidden_kernel<<<2048, 256, 0, stream>>>(hidden, Abf, (M_TOTAL * KDIM) / 8);
  gemm_bias_res_kernel<<<(M_TOTAL / BM) * (NDIM / BN), 256, 0, stream>>>(Abf, Bq, bias, resid, out);
}

// Round 3
// 574.040 us; speedup vs baseline: 1.1561x; 1.1561x over previous
//
#include <hip/hip_runtime.h>
#include <hip/hip_bf16.h>
#include <stdint.h>

// QuantizedViTOutput: fake-quant(W, 8-bit per-row symmetric) GEMM + bias + residual.
// M=16384 (B*S), K=4096 (D_FF), N=1024 (D). fp32 in / fp32 out.
// Round 3: 256x256 8-wave double-buffered 8-phase GEMM (T1 XCD swizzle + T2 LDS
// XOR-swizzle + T3/T4 phased prefetch with distance-based drain + T5 setprio).

#define M_TOTAL 16384
#define KDIM    4096
#define NDIM    1024
#define BM      256
#define BN      256
#define BK      64
#define NT      (KDIM / BK)       // 64 K-tiles
#define BUF_BYTES 65536           // A 32KB + B 32KB per K-tile buffer
#define B_OFF   32768             // B region offset within a buffer

using f32x4  = __attribute__((ext_vector_type(4))) float;
using bf16x8 = __attribute__((ext_vector_type(8))) __bf16;
using u16x8  = __attribute__((ext_vector_type(8))) unsigned short;

__device__ __forceinline__ unsigned short f32_to_bf16_bits(float f) {
  union { float f; uint32_t u; } x; x.f = f;
  uint32_t r = x.u + 0x7FFFu + ((x.u >> 16) & 1u);   // RNE
  return (unsigned short)(r >> 16);
}

__device__ __forceinline__ void async_copy16(const void* g, void* l) {
  __builtin_amdgcn_global_load_lds(
      (const __attribute__((address_space(1))) void*)g,
      (__attribute__((address_space(3))) void*)l,
      16, 0, 0);   // 16B/lane, wave-uniform LDS base + lane*16
}

// ---------------- kernel 1: per-output-channel fake-quant of W -> bf16 ----------------
__global__ __launch_bounds__(256) void quantize_w_kernel(
    const float* __restrict__ W, unsigned short* __restrict__ Bq) {
  const int row = blockIdx.x;
  const int t   = threadIdx.x;
  const f32x4* wv = (const f32x4*)(W + (size_t)row * KDIM);

  f32x4 v[4];
  float m = 0.0f;
#pragma unroll
  for (int i = 0; i < 4; ++i) {
    v[i] = wv[t * 4 + i];
#pragma unroll
    for (int j = 0; j < 4; ++j) m = fmaxf(m, fabsf(v[i][j]));
  }
#pragma unroll
  for (int off = 32; off >= 1; off >>= 1) m = fmaxf(m, __shfl_xor(m, off));
  __shared__ float smax[4];
  if ((t & 63) == 0) smax[t >> 6] = m;
  __syncthreads();
  m = fmaxf(fmaxf(smax[0], smax[1]), fmaxf(smax[2], smax[3]));

  const float scale = fmaxf(m, 1e-8f) / 127.0f;

  u16x8 o[2];
#pragma unroll
  for (int i = 0; i < 16; ++i) {
    float w = v[i >> 2][i & 3];
    float q = rintf(w / scale);                    // fp32 IEEE div + RNE = jnp.round(W/scale)
    q = fminf(127.0f, fmaxf(-128.0f, q));
    o[i >> 3][i & 7] = f32_to_bf16_bits(q * scale);
  }
  u16x8* dst = (u16x8*)(Bq + (size_t)row * KDIM + t * 16);
  dst[0] = o[0];
  dst[1] = o[1];
}

// ---------------- kernel 2: cast hidden fp32 -> bf16 (vectorized) ----------------
__global__ __launch_bounds__(256) void cast_hidden_kernel(
    const float* __restrict__ A, unsigned short* __restrict__ Ab, int n8) {
  const int stride = gridDim.x * blockDim.x;
  for (int i = blockIdx.x * blockDim.x + threadIdx.x; i < n8; i += stride) {
    const f32x4* src = (const f32x4*)A + (size_t)i * 2;
    f32x4 a = src[0], b = src[1];
    u16x8 o;
#pragma unroll
    for (int j = 0; j < 4; ++j) o[j]     = f32_to_bf16_bits(a[j]);
#pragma unroll
    for (int j = 0; j < 4; ++j) o[4 + j] = f32_to_bf16_bits(b[j]);
    ((u16x8*)Ab)[i] = o;
  }
}

// ---------------- kernel 3: 256^2 8-wave phased bf16 MFMA GEMM + bias + residual ----
// A: [M][K] bf16, Bq: [N][K] bf16. out = A.Bq^T + bias + res (fp32).
// LDS per buffer: A-tile 256x64 bf16 (rows of 128B, slot s=16B chunk stored at
// s ^ (row&7)), then B-tile same at +32KB. Two buffers (tile parity).
__global__ __launch_bounds__(512, 2) void gemm_8phase_kernel(
    const unsigned short* __restrict__ A,
    const unsigned short* __restrict__ Bq,
    const float* __restrict__ bias,
    const float* __restrict__ res,
    float* __restrict__ out) {
  __shared__ char smem[2 * BUF_BYTES];   // 128 KiB

  const int nwg = (M_TOTAL / BM) * (NDIM / BN);   // 256, %8==0 -> simple bijective swizzle
  int bid = blockIdx.x;
  bid = (bid & 7) * (nwg >> 3) + (bid >> 3);      // XCD-aware
  const int nb = bid & 3;                          // N fastest: A-panel (2MB) reused 4x in-XCD L2
  const int mb = bid >> 2;
  const int m0 = mb * BM, n0 = nb * BN;

  const int tid  = threadIdx.x;
  const int lane = tid & 63;
  const int wid  = tid >> 6;     // 8 waves: wm in {0,1}, wn in {0..3}
  const int wm   = wid >> 2;
  const int wn   = wid & 3;

  // ---- staging addressing (write side: linear LDS dest, inverse-swizzled source) ----
  // per call i (0..3): wave wid stages rows i*64 + wid*8 .. +7 (8 rows x 8 slots = 64 lanes)
  const int srow  = lane >> 3;                       // row within wave's 8
  const int scol8 = (lane & 7) ^ (srow & 7);         // source chunk for this lane's slot
  const unsigned short* agp[4];
  const unsigned short* bgp[4];
#pragma unroll
  for (int i = 0; i < 4; ++i) {
    agp[i] = A  + (size_t)(m0 + i * 64 + wid * 8 + srow) * KDIM + scol8 * 8;
    bgp[i] = Bq + (size_t)(n0 + i * 64 + wid * 8 + srow) * KDIM + scol8 * 8;
  }

#define STAGE(BUFBASE, K0) do {                                              \
    _Pragma("unroll")                                                        \
    for (int i_ = 0; i_ < 4; ++i_) {                                         \
      async_copy16(agp[i_] + (K0), (BUFBASE) + (i_ * 64 + wid * 8) * 128);   \
      async_copy16(bgp[i_] + (K0), (BUFBASE) + B_OFF + (i_ * 64 + wid * 8) * 128); \
    }                                                                        \
  } while (0)

  // ---- fragment read addressing (swizzled) ----
  const int fr = lane & 15;            // fragment row within 16
  const int kg = lane >> 4;            // k-group (8 bf16 each)
  const int cs0 = ((kg)     ^ (fr & 7)) * 16;   // kk=0 swizzled slot byte
  const int cs1 = ((kg + 4) ^ (fr & 7)) * 16;   // kk=1
  const int baseA = (wm * 128 + fr) * 128;             // + mi*2048 + cs
  const int baseB = B_OFF + (wn * 64 + fr) * 128;      // + nj*2048 + cs

  f32x4 acc[8][4];
  const f32x4 zero = {0.f, 0.f, 0.f, 0.f};
#pragma unroll
  for (int i = 0; i < 8; ++i)
#pragma unroll
    for (int j = 0; j < 4; ++j) acc[i][j] = zero;

#define LDA4(MB, CS) do {                                                    \
    _Pragma("unroll")                                                        \
    for (int q_ = 0; q_ < 4; ++q_)                                           \
      a[q_] = *(const bf16x8*)(cur + baseA + ((MB) + q_) * 2048 + (CS));     \
  } while (0)
#define LDB4(CS) do {                                                        \
    _Pragma("unroll")                                                        \
    for (int q_ = 0; q_ < 4; ++q_)                                           \
      b[q_] = *(const bf16x8*)(cur + baseB + q_ * 2048 + (CS));              \
  } while (0)
#define MFMA16(MB) do {                                                      \
    __builtin_amdgcn_s_setprio(1);                                           \
    _Pragma("unroll")                                                        \
    for (int mi_ = 0; mi_ < 4; ++mi_)                                        \
      _Pragma("unroll")                                                      \
      for (int nj_ = 0; nj_ < 4; ++nj_)                                      \
        acc[(MB) + mi_][nj_] = __builtin_amdgcn_mfma_f32_16x16x32_bf16(      \
            a[mi_], b[nj_], acc[(MB) + mi_][nj_], 0, 0, 0);                  \
    __builtin_amdgcn_s_setprio(0);                                           \
  } while (0)

  // prologue: tile 0 -> buf0
  STAGE(smem, 0);
  asm volatile("s_waitcnt vmcnt(0)" ::: "memory");
  __builtin_amdgcn_s_barrier();

  for (int tt = 0; tt < NT; ++tt) {
    char* cur = smem + (tt & 1) * BUF_BYTES;
    char* nxt = smem + ((tt + 1) & 1) * BUF_BYTES;
    bf16x8 a[4], b[4];

    // P1: prefetch tile tt+1 into the buffer last read at iter tt-1 (legal after
    // the iter-start barrier); then 8 ds_reads + 16 MFMA.
    if (tt + 1 < NT) STAGE(nxt, (tt + 1) * BK);
    LDA4(0, cs0); LDB4(cs0);
    MFMA16(0);
    __builtin_amdgcn_s_barrier();

    // P2: A m4..7 kk0 (B regs reused)
    LDA4(4, cs0);
    MFMA16(4);
    __builtin_amdgcn_s_barrier();

    // P3: A m0..3 kk1 + B kk1
    LDA4(0, cs1); LDB4(cs1);
    MFMA16(0);
    __builtin_amdgcn_s_barrier();

    // P4: A m4..7 kk1; then drain this iter's prefetch (issued ~4 phases ago,
    // latency already elapsed) and cross into the next tile.
    LDA4(4, cs1);
    MFMA16(4);
    asm volatile("s_waitcnt vmcnt(0)" ::: "memory");
    __builtin_amdgcn_s_barrier();
  }

  // epilogue: C/D layout col=lane&15, row=(lane>>4)*4+reg (verified m89/m91)
  const int col = lane & 15;
  const int rg  = (lane >> 4) * 4;
#pragma unroll
  for (int nj = 0; nj < 4; ++nj) {
    const int d = n0 + wn * 64 + nj * 16 + col;
    const float bb = bias[d];
#pragma unroll
    for (int mi = 0; mi < 8; ++mi) {
      const int mrow = m0 + wm * 128 + mi * 16 + rg;
#pragma unroll
      for (int r = 0; r < 4; ++r) {
        const size_t idx = (size_t)(mrow + r) * NDIM + d;
        out[idx] = acc[mi][nj][r] + bb + res[idx];
      }
    }
  }
#undef STAGE
#undef LDA4
#undef LDB4
#undef MFMA16
}

extern "C" void kernel_launch(void* const* d_in, const int* in_sizes, int n_in,
                              void* d_out, int out_size, void* d_ws, size_t ws_size,
                              hipStream_t stream) {
  const float* hidden = (const float*)d_in[0];   // [16,1024,4096] fp32
  const float* resid  = (const float*)d_in[1];   // [16,1024,1024] fp32
  const float* W      = (const float*)d_in[2];   // [1024,4096] fp32
  const float* bias   = (const float*)d_in[3];   // [1024] fp32
  float* out          = (float*)d_out;           // [16,1024,1024] fp32

  unsigned short* Abf = (unsigned short*)d_ws;               // 134.2 MB
  unsigned short* Bq  = Abf + (size_t)M_TOTAL * KDIM;        // 8.4 MB

  quantize_w_kernel<<<NDIM, 256, 0, stream>>>(W, Bq);
  cast_hidden_kernel<<<2048, 256, 0, stream>>>(hidden, Abf, (M_TOTAL * KDIM) / 8);
  gemm_8phase_kernel<<<(M_TOTAL / BM) * (NDIM / BN), 512, 0, stream>>>(Abf, Bq, bias, resid, out);
}

// Round 4
// 558.625 us; speedup vs baseline: 1.1880x; 1.0276x over previous
//
#include <hip/hip_runtime.h>
#include <hip/hip_bf16.h>
#include <stdint.h>

// QuantizedViTOutput: fake-quant(W, 8-bit per-row symmetric) GEMM + bias + residual.
// M=16384 (B*S), K=4096 (D_FF), N=1024 (D). fp32 in / fp32 out.
// Round 4: counted-vmcnt 8-barrier schedule (T3+T4 proper). Staging spread in 4
// half-tile batches per K-tile, issue order == next-iter consumption order;
// vmcnt(2) at P1/P4 ends (never 0 in steady state). 2 barriers per phase
// (batched ds_read issue, then batched MFMA) per the m201 template.

#define M_TOTAL 16384
#define KDIM    4096
#define NDIM    1024
#define BM      256
#define BN      256
#define BK      64
#define NT      (KDIM / BK)       // 64 K-tiles
#define BUF_BYTES 65536           // A 32KB + B 32KB per K-tile buffer
#define B_OFF   32768             // B region offset within a buffer

using f32x4  = __attribute__((ext_vector_type(4))) float;
using bf16x8 = __attribute__((ext_vector_type(8))) __bf16;
using u16x8  = __attribute__((ext_vector_type(8))) unsigned short;

__device__ __forceinline__ unsigned short f32_to_bf16_bits(float f) {
  union { float f; uint32_t u; } x; x.f = f;
  uint32_t r = x.u + 0x7FFFu + ((x.u >> 16) & 1u);   // RNE
  return (unsigned short)(r >> 16);
}

__device__ __forceinline__ void async_copy16(const void* g, void* l) {
  __builtin_amdgcn_global_load_lds(
      (const __attribute__((address_space(1))) void*)g,
      (__attribute__((address_space(3))) void*)l,
      16, 0, 0);   // 16B/lane, wave-uniform LDS base + lane*16
}

// ---------------- kernel 1: per-output-channel fake-quant of W -> bf16 ----------------
__global__ __launch_bounds__(256) void quantize_w_kernel(
    const float* __restrict__ W, unsigned short* __restrict__ Bq) {
  const int row = blockIdx.x;
  const int t   = threadIdx.x;
  const f32x4* wv = (const f32x4*)(W + (size_t)row * KDIM);

  f32x4 v[4];
  float m = 0.0f;
#pragma unroll
  for (int i = 0; i < 4; ++i) {
    v[i] = wv[t * 4 + i];
#pragma unroll
    for (int j = 0; j < 4; ++j) m = fmaxf(m, fabsf(v[i][j]));
  }
#pragma unroll
  for (int off = 32; off >= 1; off >>= 1) m = fmaxf(m, __shfl_xor(m, off));
  __shared__ float smax[4];
  if ((t & 63) == 0) smax[t >> 6] = m;
  __syncthreads();
  m = fmaxf(fmaxf(smax[0], smax[1]), fmaxf(smax[2], smax[3]));

  const float scale = fmaxf(m, 1e-8f) / 127.0f;

  u16x8 o[2];
#pragma unroll
  for (int i = 0; i < 16; ++i) {
    float w = v[i >> 2][i & 3];
    float q = rintf(w / scale);                    // fp32 IEEE div + RNE = jnp.round(W/scale)
    q = fminf(127.0f, fmaxf(-128.0f, q));
    o[i >> 3][i & 7] = f32_to_bf16_bits(q * scale);
  }
  u16x8* dst = (u16x8*)(Bq + (size_t)row * KDIM + t * 16);
  dst[0] = o[0];
  dst[1] = o[1];
}

// ---------------- kernel 2: cast hidden fp32 -> bf16 (vectorized) ----------------
__global__ __launch_bounds__(256) void cast_hidden_kernel(
    const float* __restrict__ A, unsigned short* __restrict__ Ab, int n8) {
  const int stride = gridDim.x * blockDim.x;
  for (int i = blockIdx.x * blockDim.x + threadIdx.x; i < n8; i += stride) {
    const f32x4* src = (const f32x4*)A + (size_t)i * 2;
    f32x4 a = src[0], b = src[1];
    u16x8 o;
#pragma unroll
    for (int j = 0; j < 4; ++j) o[j]     = f32_to_bf16_bits(a[j]);
#pragma unroll
    for (int j = 0; j < 4; ++j) o[4 + j] = f32_to_bf16_bits(b[j]);
    ((u16x8*)Ab)[i] = o;
  }
}

// ---------------- kernel 3: 256^2 8-wave counted-vmcnt bf16 MFMA GEMM ----------------
// A: [M][K] bf16, Bq: [N][K] bf16. out = A.Bq^T + bias + res (fp32).
// LDS buffer: A-tile 256x64 bf16 rows of 128B (16B slot s stored at s^(row&7)),
// B-tile at +32KB. Two buffers (tile parity).
__global__ __launch_bounds__(512, 2) void gemm_8phase_kernel(
    const unsigned short* __restrict__ A,
    const unsigned short* __restrict__ Bq,
    const float* __restrict__ bias,
    const float* __restrict__ res,
    float* __restrict__ out) {
  __shared__ char smem[2 * BUF_BYTES];   // 128 KiB

  const int nwg = (M_TOTAL / BM) * (NDIM / BN);   // 256, %8==0 -> simple bijective swizzle
  int bid = blockIdx.x;
  bid = (bid & 7) * (nwg >> 3) + (bid >> 3);      // XCD-aware
  const int nb = bid & 3;                          // N fastest: A-panel reused in-XCD L2
  const int mb = bid >> 2;
  const int m0 = mb * BM, n0 = nb * BN;

  const int tid  = threadIdx.x;
  const int lane = tid & 63;
  const int wid  = tid >> 6;     // 8 waves: wm in {0,1}, wn in {0..3}
  const int wm   = wid >> 1;     // (unused pattern retained below)
  const int wmm  = wid >> 2;
  const int wn   = wid & 3;
  (void)wm;

  // ---- staging addressing (linear LDS dest, inverse-swizzled global source) ----
  // call i (0..3): wave wid stages rows i*64 + wid*8 .. +7 (8 rows x 8 chunks of 16B)
  const int srow  = lane >> 3;
  const int scol8 = (lane & 7) ^ (srow & 7);
  const unsigned short* agp[4];
  const unsigned short* bgp[4];
#pragma unroll
  for (int i = 0; i < 4; ++i) {
    agp[i] = A  + (size_t)(m0 + i * 64 + wid * 8 + srow) * KDIM + scol8 * 8;
    bgp[i] = Bq + (size_t)(n0 + i * 64 + wid * 8 + srow) * KDIM + scol8 * 8;
  }

  // Batch = 2 gload_lds. Consumption next iter: P1 reads all B + A rows{0-63,128-191};
  // P2 reads A rows{64-127,192-255}. Issue order B1,B2,A1,A2 matches need order.
#define STG_B1(BUF, K0) do { async_copy16(bgp[0] + (K0), (BUF) + B_OFF + (0 * 64 + wid * 8) * 128); \
                             async_copy16(bgp[1] + (K0), (BUF) + B_OFF + (1 * 64 + wid * 8) * 128); } while (0)
#define STG_B2(BUF, K0) do { async_copy16(bgp[2] + (K0), (BUF) + B_OFF + (2 * 64 + wid * 8) * 128); \
                             async_copy16(bgp[3] + (K0), (BUF) + B_OFF + (3 * 64 + wid * 8) * 128); } while (0)
#define STG_A1(BUF, K0) do { async_copy16(agp[0] + (K0), (BUF) + (0 * 64 + wid * 8) * 128); \
                             async_copy16(agp[2] + (K0), (BUF) + (2 * 64 + wid * 8) * 128); } while (0)
#define STG_A2(BUF, K0) do { async_copy16(agp[1] + (K0), (BUF) + (1 * 64 + wid * 8) * 128); \
                             async_copy16(agp[3] + (K0), (BUF) + (3 * 64 + wid * 8) * 128); } while (0)

  // ---- fragment read addressing (swizzled) ----
  const int fr = lane & 15;            // fragment row within 16
  const int kg = lane >> 4;            // k-group (8 bf16)
  const int cs0 = ((kg)     ^ (fr & 7)) * 16;   // kk=0 swizzled chunk byte
  const int cs1 = ((kg + 4) ^ (fr & 7)) * 16;   // kk=1
  const int baseA = (wmm * 128 + fr) * 128;            // + mi*2048 + cs
  const int baseB = B_OFF + (wn * 64 + fr) * 128;      // + nj*2048 + cs

  f32x4 acc[8][4];
  const f32x4 zero = {0.f, 0.f, 0.f, 0.f};
#pragma unroll
  for (int i = 0; i < 8; ++i)
#pragma unroll
    for (int j = 0; j < 4; ++j) acc[i][j] = zero;

#define LDA4(MB, CS) do {                                                    \
    _Pragma("unroll")                                                        \
    for (int q_ = 0; q_ < 4; ++q_)                                           \
      a[q_] = *(const bf16x8*)(cur + baseA + ((MB) + q_) * 2048 + (CS));     \
  } while (0)
#define LDB4(CS) do {                                                        \
    _Pragma("unroll")                                                        \
    for (int q_ = 0; q_ < 4; ++q_)                                           \
      b[q_] = *(const bf16x8*)(cur + baseB + q_ * 2048 + (CS));              \
  } while (0)
#define MFMA16(MB) do {                                                      \
    __builtin_amdgcn_s_setprio(1);                                           \
    _Pragma("unroll")                                                        \
    for (int mi_ = 0; mi_ < 4; ++mi_)                                        \
      _Pragma("unroll")                                                      \
      for (int nj_ = 0; nj_ < 4; ++nj_)                                      \
        acc[(MB) + mi_][nj_] = __builtin_amdgcn_mfma_f32_16x16x32_bf16(      \
            a[mi_], b[nj_], acc[(MB) + mi_][nj_], 0, 0, 0);                  \
    __builtin_amdgcn_s_setprio(0);                                           \
  } while (0)
#define BAR()    __builtin_amdgcn_s_barrier()
#define VMCNT2() asm volatile("s_waitcnt vmcnt(2)" ::: "memory")
#define VMCNT0() asm volatile("s_waitcnt vmcnt(0)" ::: "memory")

  // prologue: tile 0 -> buf0, drain, barrier
  STG_B1(smem, 0); STG_B2(smem, 0); STG_A1(smem, 0); STG_A2(smem, 0);
  VMCNT0();
  BAR();

  for (int tt = 0; tt < NT; ++tt) {
    char* cur = smem + (tt & 1) * BUF_BYTES;
    char* nxt = smem + ((tt + 1) & 1) * BUF_BYTES;
    const int k1 = (tt + 1) * BK;
    const bool pf = (tt + 1 < NT);
    bf16x8 a[4], b[4];

    // P1: ds_read A(rows h1) kk0 + B kk0; stage B1(t+1); MFMA quadrant m0..3.
    LDA4(0, cs0); LDB4(cs0);
    if (pf) STG_B1(nxt, k1);
    BAR();
    MFMA16(0);
    if (pf) VMCNT2(); else VMCNT0();   // land A2(cur) before P2 reads it
    BAR();

    // P2: A(rows h2) kk0; stage B2(t+1); MFMA m4..7. (B regs reused)
    LDA4(4, cs0);
    if (pf) STG_B2(nxt, k1);
    BAR();
    MFMA16(4);
    BAR();

    // P3: A h1 kk1 + B kk1; stage A1(t+1); MFMA m0..3.
    LDA4(0, cs1); LDB4(cs1);
    if (pf) STG_A1(nxt, k1);
    BAR();
    MFMA16(0);
    BAR();

    // P4: A h2 kk1; stage A2(t+1); MFMA m4..7; land B1,B2,A1(t+1) (leave A2 in flight).
    LDA4(4, cs1);
    if (pf) STG_A2(nxt, k1);
    BAR();
    MFMA16(4);
    VMCNT2();
    BAR();
  }

  // epilogue: C/D layout col=lane&15, row=(lane>>4)*4+reg (verified m89/m91)
  const int col = lane & 15;
  const int rg  = (lane >> 4) * 4;
#pragma unroll
  for (int nj = 0; nj < 4; ++nj) {
    const int d = n0 + wn * 64 + nj * 16 + col;
    const float bb = bias[d];
#pragma unroll
    for (int mi = 0; mi < 8; ++mi) {
      const int mrow = m0 + wmm * 128 + mi * 16 + rg;
#pragma unroll
      for (int r = 0; r < 4; ++r) {
        const size_t idx = (size_t)(mrow + r) * NDIM + d;
        out[idx] = acc[mi][nj][r] + bb + res[idx];
      }
    }
  }
#undef STG_B1
#undef STG_B2
#undef STG_A1
#undef STG_A2
#undef LDA4
#undef LDB4
#undef MFMA16
#undef BAR
#undef VMCNT2
#undef VMCNT0
}

extern "C" void kernel_launch(void* const* d_in, const int* in_sizes, int n_in,
                              void* d_out, int out_size, void* d_ws, size_t ws_size,
                              hipStream_t stream) {
  const float* hidden = (const float*)d_in[0];   // [16,1024,4096] fp32
  const float* resid  = (const float*)d_in[1];   // [16,1024,1024] fp32
  const float* W      = (const float*)d_in[2];   // [1024,4096] fp32
  const float* bias   = (const float*)d_in[3];   // [1024] fp32
  float* out          = (float*)d_out;           // [16,1024,1024] fp32

  unsigned short* Abf = (unsigned short*)d_ws;               // 134.2 MB
  unsigned short* Bq  = Abf + (size_t)M_TOTAL * KDIM;        // 8.4 MB

  quantize_w_kernel<<<NDIM, 256, 0, stream>>>(W, Bq);
  cast_hidden_kernel<<<2048, 256, 0, stream>>>(hidden, Abf, (M_TOTAL * KDIM) / 8);
  gemm_8phase_kernel<<<(M_TOTAL / BM) * (NDIM / BN), 512, 0, stream>>>(Abf, Bq, bias, resid, out);
}